// Round 1
// baseline (184.746 us; speedup 1.0000x reference)
//
#include <hip/hip_runtime.h>
#include <hip/hip_bf16.h>
#include <stdint.h>

// Problem constants
#define BB 4
#define NN 2048
#define DIMD 512
#define HH 8
#define DKK 64
#define MTOT (BB * NN)          // 8192
constexpr float SCALE = 0.125f; // DK^-0.5

typedef __attribute__((ext_vector_type(4))) float f32x4;
typedef __attribute__((ext_vector_type(8))) short bf16x8; // 8 bf16 in 4 VGPRs

__device__ __forceinline__ unsigned short f2bf(float f) {
  union { float f; uint32_t u; } v; v.f = f;
  uint32_t u = v.u;
  return (unsigned short)((u + 0x7FFFu + ((u >> 16) & 1u)) >> 16); // RNE
}

__device__ __forceinline__ float fast_sigmoid(float x) {
  return __builtin_amdgcn_rcpf(1.0f + __expf(-x));
}

// ---------------------------------------------------------------------------
// prep_x: x fp32 [B][N][DIM] -> xb bf16 [B*N][DIM]  and  xt bf16 [B][DIM][N]
// grid: (32 n-tiles, 8 d-tiles, 4 batch), 256 threads
// ---------------------------------------------------------------------------
__global__ __launch_bounds__(256) void prep_x(const float* __restrict__ x,
                                              unsigned short* __restrict__ xb,
                                              unsigned short* __restrict__ xt) {
  __shared__ __align__(16) unsigned short T[64][72];
  const int b = blockIdx.z, nt = blockIdx.x, dt = blockIdx.y;
  const int tid = threadIdx.x;
  const int n0 = nt * 64, d0 = dt * 64;
  const float* src = x + ((size_t)b * NN + n0) * DIMD + d0;
#pragma unroll
  for (int r = 0; r < 16; r++) {
    int idx = tid + r * 256;
    int nl = idx >> 6, dl = idx & 63;
    unsigned short bv = f2bf(src[(size_t)nl * DIMD + dl]);
    xb[((size_t)b * NN + n0 + nl) * DIMD + d0 + dl] = bv;
    T[dl][nl] = bv;
  }
  __syncthreads();
  unsigned short* dst = xt + ((size_t)b * DIMD + d0) * NN + n0;
#pragma unroll
  for (int r = 0; r < 16; r++) {
    int idx = tid + r * 256;
    int dl = idx >> 6, nl = idx & 63;
    dst[(size_t)dl * NN + nl] = T[dl][nl];
  }
}

// ---------------------------------------------------------------------------
// prep_w: W fp32 [K=512][N=512] -> Wt bf16 [N][K]
// grid: (8 k-tiles, 8 n-tiles), 256 threads
// ---------------------------------------------------------------------------
__global__ __launch_bounds__(256) void prep_w(const float* __restrict__ w,
                                              unsigned short* __restrict__ wt) {
  __shared__ __align__(16) unsigned short T[64][72];
  const int kt = blockIdx.x, nt = blockIdx.y;
  const int tid = threadIdx.x;
  const int k0 = kt * 64, n0 = nt * 64;
#pragma unroll
  for (int r = 0; r < 16; r++) {
    int idx = tid + r * 256;
    int kl = idx >> 6, nl = idx & 63;
    T[nl][kl] = f2bf(w[(size_t)(k0 + kl) * DIMD + n0 + nl]);
  }
  __syncthreads();
#pragma unroll
  for (int r = 0; r < 16; r++) {
    int idx = tid + r * 256;
    int nl = idx >> 6, kl = idx & 63;
    wt[(size_t)(n0 + nl) * DIMD + k0 + kl] = T[nl][kl];
  }
}

// ---------------------------------------------------------------------------
// qk_gemm: y = xb @ W  (W given transposed, bf16)
//   grid.x = 128 m-blocks (64 rows), grid.y = 16 n-blocks (0..7 -> Q w/ scale
//   + bias epilogue, 8..15 -> K). 256 threads = 4 waves, each wave 16 rows.
// ---------------------------------------------------------------------------
__global__ __launch_bounds__(256) void qk_gemm(const unsigned short* __restrict__ xb,
                                               const unsigned short* __restrict__ wtq,
                                               const unsigned short* __restrict__ wtk,
                                               const float* __restrict__ bias, // [512]
                                               unsigned short* __restrict__ qout,
                                               unsigned short* __restrict__ kout) {
  __shared__ __align__(16) unsigned short Als[64][72];
  __shared__ __align__(16) unsigned short Bls[64][72];
  const int mb = blockIdx.x, nb = blockIdx.y;
  const bool isQ = (nb < 8);
  const unsigned short* wt = isQ ? wtq : wtk;
  unsigned short* out = isQ ? qout : kout;
  const int n0 = (nb & 7) * 64;
  const int m0 = mb * 64;
  const int tid = threadIdx.x;
  const int wave = tid >> 6, lane = tid & 63;
  const int quad = lane >> 4, l16 = lane & 15;

  f32x4 acc[4];
#pragma unroll
  for (int t = 0; t < 4; t++) acc[t] = (f32x4){0.f, 0.f, 0.f, 0.f};

  for (int k0 = 0; k0 < DIMD; k0 += 64) {
    __syncthreads();
#pragma unroll
    for (int r = 0; r < 2; r++) {
      int idx = tid + r * 256;          // 0..511
      int row = idx >> 3, c = idx & 7;  // row 0..63, 16B chunk 0..7
      *(uint4*)&Als[row][c * 8] =
          *(const uint4*)(xb + (size_t)(m0 + row) * DIMD + k0 + c * 8);
      *(uint4*)&Bls[row][c * 8] =
          *(const uint4*)(wt + (size_t)(n0 + row) * DIMD + k0 + c * 8);
    }
    __syncthreads();
#pragma unroll
    for (int ks = 0; ks < 2; ks++) {
      bf16x8 af = *(const bf16x8*)&Als[wave * 16 + l16][quad * 8 + ks * 32];
#pragma unroll
      for (int t = 0; t < 4; t++) {
        bf16x8 bf = *(const bf16x8*)&Bls[t * 16 + l16][quad * 8 + ks * 32];
        acc[t] = __builtin_amdgcn_mfma_f32_16x16x32_bf16(af, bf, acc[t], 0, 0, 0);
      }
    }
  }
  // epilogue: C layout col=lane&15, row=quad*4+reg
#pragma unroll
  for (int t = 0; t < 4; t++) {
#pragma unroll
    for (int r = 0; r < 4; r++) {
      int row = m0 + wave * 16 + quad * 4 + r;
      int col = n0 + t * 16 + l16;
      float v = acc[t][r];
      if (isQ) v = v * SCALE + bias[col]; // bias flat [h*64+d] == global col
      out[(size_t)row * DIMD + col] = f2bf(v);
    }
  }
}

// ---------------------------------------------------------------------------
// attn: per (b,h): O = sigmoid(Q K^T) V    (no softmax normalization)
//   grid.x = 32 i-tiles (64 rows), grid.y = 32 (b*8+h). 4 waves, 16 rows each.
//   Q from qb [B*N][512] (scale+bias pre-applied), K from kb, V = xt rows.
// ---------------------------------------------------------------------------
__global__ __launch_bounds__(256) void attn(const unsigned short* __restrict__ qb,
                                            const unsigned short* __restrict__ kb,
                                            const unsigned short* __restrict__ xt,
                                            float* __restrict__ out) {
  __shared__ __align__(16) unsigned short Kls[64][72];
  __shared__ __align__(16) unsigned short Vtls[64][72];
  __shared__ __align__(16) unsigned short Pls[4][16][72];
  const int it = blockIdx.x, bh = blockIdx.y;
  const int b = bh >> 3, h = bh & 7;
  const int i0 = it * 64;
  const int tid = threadIdx.x;
  const int wave = tid >> 6, lane = tid & 63;
  const int quad = lane >> 4, l16 = lane & 15;

  // Q A-fragments: row i = i0 + wave*16 + l16, k(d) = quad*8 + ks*32 + [0..7]
  bf16x8 qfrag[2];
  {
    const unsigned short* qp =
        qb + ((size_t)b * NN + i0 + wave * 16 + l16) * DIMD + h * DKK + quad * 8;
    qfrag[0] = *(const bf16x8*)qp;
    qfrag[1] = *(const bf16x8*)(qp + 32);
  }

  f32x4 o[4];
#pragma unroll
  for (int t = 0; t < 4; t++) o[t] = (f32x4){0.f, 0.f, 0.f, 0.f};

  const unsigned short* kbase = kb + (size_t)b * NN * DIMD + h * DKK;
  const unsigned short* vtbase = xt + ((size_t)b * DIMD + h * DKK) * NN;

  for (int j0 = 0; j0 < NN; j0 += 64) {
    __syncthreads();
#pragma unroll
    for (int r = 0; r < 2; r++) {
      int idx = tid + r * 256;
      int row = idx >> 3, c = idx & 7;
      *(uint4*)&Kls[row][c * 8] =
          *(const uint4*)(kbase + (size_t)(j0 + row) * DIMD + c * 8);
      *(uint4*)&Vtls[row][c * 8] =
          *(const uint4*)(vtbase + (size_t)row * NN + j0 + c * 8);
    }
    __syncthreads();

    // S = Q K^T, then sigmoid -> P (bf16) into per-wave LDS (A-layout source)
#pragma unroll
    for (int t = 0; t < 4; t++) {
      f32x4 s = (f32x4){0.f, 0.f, 0.f, 0.f};
      bf16x8 b0 = *(const bf16x8*)&Kls[t * 16 + l16][quad * 8];
      s = __builtin_amdgcn_mfma_f32_16x16x32_bf16(qfrag[0], b0, s, 0, 0, 0);
      bf16x8 b1 = *(const bf16x8*)&Kls[t * 16 + l16][quad * 8 + 32];
      s = __builtin_amdgcn_mfma_f32_16x16x32_bf16(qfrag[1], b1, s, 0, 0, 0);
#pragma unroll
      for (int r = 0; r < 4; r++) {
        Pls[wave][quad * 4 + r][t * 16 + l16] = f2bf(fast_sigmoid(s[r]));
      }
    }

    // O += P V : A = P (m=i local row = l16), B = Vt (n=d = l16, k=j)
#pragma unroll
    for (int ks = 0; ks < 2; ks++) {
      bf16x8 pf = *(const bf16x8*)&Pls[wave][l16][ks * 32 + quad * 8];
#pragma unroll
      for (int td = 0; td < 4; td++) {
        bf16x8 vf = *(const bf16x8*)&Vtls[td * 16 + l16][ks * 32 + quad * 8];
        o[td] = __builtin_amdgcn_mfma_f32_16x16x32_bf16(pf, vf, o[td], 0, 0, 0);
      }
    }
  }

  // epilogue: out[b][i][h*64 + d] fp32
#pragma unroll
  for (int td = 0; td < 4; td++) {
#pragma unroll
    for (int r = 0; r < 4; r++) {
      int row = i0 + wave * 16 + quad * 4 + r;
      out[((size_t)b * NN + row) * DIMD + h * DKK + td * 16 + l16] = o[td][r];
    }
  }
}

// ---------------------------------------------------------------------------
extern "C" void kernel_launch(void* const* d_in, const int* in_sizes, int n_in,
                              void* d_out, int out_size, void* d_ws, size_t ws_size,
                              hipStream_t stream) {
  const float* x = (const float*)d_in[0];
  const float* Wq = (const float*)d_in[1];
  const float* Wk = (const float*)d_in[2];
  const float* bias = (const float*)d_in[3]; // [1,8,1,64] flat = 512
  float* out = (float*)d_out;

  unsigned short* ws = (unsigned short*)d_ws;
  unsigned short* xb = ws;                    // 8192*512 = 4,194,304
  unsigned short* xt = xb + (size_t)MTOT * DIMD;   // 4,194,304
  unsigned short* wtq = xt + (size_t)MTOT * DIMD;  // 262,144
  unsigned short* wtk = wtq + (size_t)DIMD * DIMD; // 262,144
  unsigned short* qb = wtk + (size_t)DIMD * DIMD;  // 4,194,304
  unsigned short* kb = qb + (size_t)MTOT * DIMD;   // 4,194,304
  // total = 17,301,504 shorts = 34.6 MB of d_ws

  prep_x<<<dim3(32, 8, 4), 256, 0, stream>>>(x, xb, xt);
  prep_w<<<dim3(8, 8), 256, 0, stream>>>(Wq, wtq);
  prep_w<<<dim3(8, 8), 256, 0, stream>>>(Wk, wtk);
  qk_gemm<<<dim3(128, 16), 256, 0, stream>>>(xb, wtq, wtk, bias, qb, kb);
  attn<<<dim3(32, 32), 256, 0, stream>>>(qb, kb, xt, out);
}

// Round 3
// 180.169 us; speedup vs baseline: 1.0254x; 1.0254x over previous
//
#include <hip/hip_runtime.h>
#include <hip/hip_bf16.h>
#include <stdint.h>

// Problem constants
#define BB 4
#define NN 2048
#define DIMD 512
#define HH 8
#define DKK 64
#define MTOT (BB * NN)          // 8192
constexpr float SCALE = 0.125f; // DK^-0.5

typedef __attribute__((ext_vector_type(4))) float f32x4;
typedef __attribute__((ext_vector_type(8))) short bf16x8;   // 8 bf16 (4 VGPRs)
typedef __attribute__((ext_vector_type(4))) _Float16 f16x4; // 4 f16 (2 VGPRs)
typedef __attribute__((ext_vector_type(2))) __fp16 fp16v2;  // cvt_pkrtz result type
typedef __attribute__((ext_vector_type(4))) __fp16 fp16v4;

__device__ __forceinline__ unsigned short f2bf(float f) {
  union { float f; uint32_t u; } v; v.f = f;
  uint32_t u = v.u;
  return (unsigned short)((u + 0x7FFFu + ((u >> 16) & 1u)) >> 16); // RNE
}

__device__ __forceinline__ float sigmoidf(float x) {
  return __builtin_amdgcn_rcpf(1.0f + __expf(-x));
}

// ---------------------------------------------------------------------------
// prep_x: x fp32 [B][N][DIM] -> xb bf16 [B*N][DIM] (GEMM A)
//                           and xtf f16  [B][DIM][N] (V^T for PV f16 MFMA)
// grid: (32 n-tiles, 8 d-tiles, 4 batch), 256 threads
// ---------------------------------------------------------------------------
__global__ __launch_bounds__(256) void prep_x(const float* __restrict__ x,
                                              unsigned short* __restrict__ xb,
                                              unsigned short* __restrict__ xtf) {
  __shared__ __align__(16) unsigned short T[64][72];
  const int b = blockIdx.z, nt = blockIdx.x, dt = blockIdx.y;
  const int tid = threadIdx.x;
  const int n0 = nt * 64, d0 = dt * 64;
  const float* src = x + ((size_t)b * NN + n0) * DIMD + d0;
#pragma unroll
  for (int r = 0; r < 16; r++) {
    int idx = tid + r * 256;
    int nl = idx >> 6, dl = idx & 63;
    float f = src[(size_t)nl * DIMD + dl];
    xb[((size_t)b * NN + n0 + nl) * DIMD + d0 + dl] = f2bf(f);
    union { _Float16 h; unsigned short u; } c; c.h = (_Float16)f;
    T[dl][nl] = c.u;
  }
  __syncthreads();
  unsigned short* dst = xtf + ((size_t)b * DIMD + d0) * NN + n0;
#pragma unroll
  for (int r = 0; r < 16; r++) {
    int idx = tid + r * 256;
    int dl = idx >> 6, nl = idx & 63;
    dst[(size_t)dl * NN + nl] = T[dl][nl];
  }
}

// ---------------------------------------------------------------------------
// prep_w: W fp32 [K=512][N=512] -> Wt bf16 [N][K]; grid.z selects Wq/Wk
// ---------------------------------------------------------------------------
__global__ __launch_bounds__(256) void prep_w(const float* __restrict__ wq,
                                              const float* __restrict__ wk,
                                              unsigned short* __restrict__ wtq,
                                              unsigned short* __restrict__ wtk) {
  __shared__ __align__(16) unsigned short T[64][72];
  const float* w = blockIdx.z ? wk : wq;
  unsigned short* wt = blockIdx.z ? wtk : wtq;
  const int kt = blockIdx.x, nt = blockIdx.y;
  const int tid = threadIdx.x;
  const int k0 = kt * 64, n0 = nt * 64;
#pragma unroll
  for (int r = 0; r < 16; r++) {
    int idx = tid + r * 256;
    int kl = idx >> 6, nl = idx & 63;
    T[nl][kl] = f2bf(w[(size_t)(k0 + kl) * DIMD + n0 + nl]);
  }
  __syncthreads();
#pragma unroll
  for (int r = 0; r < 16; r++) {
    int idx = tid + r * 256;
    int nl = idx >> 6, kl = idx & 63;
    wt[(size_t)(n0 + nl) * DIMD + k0 + kl] = T[nl][kl];
  }
}

// ---------------------------------------------------------------------------
// qk_gemm: 128x128 tile, 4 waves in 2x2, each wave 64x64 (4x4 16x16 accs).
//   grid (64 m-blocks, 8 n-blocks): nb 0..3 -> Q (scale+bias), 4..7 -> K.
// ---------------------------------------------------------------------------
__global__ __launch_bounds__(256) void qk_gemm(const unsigned short* __restrict__ xb,
                                               const unsigned short* __restrict__ wtq,
                                               const unsigned short* __restrict__ wtk,
                                               const float* __restrict__ bias,
                                               unsigned short* __restrict__ qout,
                                               unsigned short* __restrict__ kout) {
  __shared__ __align__(16) unsigned short Als[128][72];
  __shared__ __align__(16) unsigned short Bls[128][72];
  const int mb = blockIdx.x, nb = blockIdx.y;
  const bool isQ = (nb < 4);
  const unsigned short* wt = isQ ? wtq : wtk;
  unsigned short* outp = isQ ? qout : kout;
  const int n0 = (nb & 3) * 128, m0 = mb * 128;
  const int tid = threadIdx.x;
  const int wave = tid >> 6, lane = tid & 63;
  const int quad = lane >> 4, l16 = lane & 15;
  const int wm = wave >> 1, wn = wave & 1;

  f32x4 acc[4][4];
#pragma unroll
  for (int a = 0; a < 4; a++)
#pragma unroll
    for (int c = 0; c < 4; c++) acc[a][c] = (f32x4){0.f, 0.f, 0.f, 0.f};

  for (int k0 = 0; k0 < DIMD; k0 += 64) {
    __syncthreads();
#pragma unroll
    for (int r = 0; r < 4; r++) {
      int idx = tid + r * 256;          // 0..1023
      int row = idx >> 3, c = idx & 7;  // 128 rows x 8 16B-chunks
      *(uint4*)&Als[row][c * 8] =
          *(const uint4*)(xb + (size_t)(m0 + row) * DIMD + k0 + c * 8);
      *(uint4*)&Bls[row][c * 8] =
          *(const uint4*)(wt + (size_t)(n0 + row) * DIMD + k0 + c * 8);
    }
    __syncthreads();
#pragma unroll
    for (int ks = 0; ks < 2; ks++) {
      bf16x8 af[4], bfr[4];
#pragma unroll
      for (int t = 0; t < 4; t++) {
        af[t] = *(const bf16x8*)&Als[wm * 64 + t * 16 + l16][quad * 8 + ks * 32];
        bfr[t] = *(const bf16x8*)&Bls[wn * 64 + t * 16 + l16][quad * 8 + ks * 32];
      }
#pragma unroll
      for (int tm = 0; tm < 4; tm++)
#pragma unroll
        for (int tn = 0; tn < 4; tn++)
          acc[tm][tn] =
              __builtin_amdgcn_mfma_f32_16x16x32_bf16(af[tm], bfr[tn], acc[tm][tn], 0, 0, 0);
    }
  }
  // epilogue: C layout col=l16, row=quad*4+r
#pragma unroll
  for (int tm = 0; tm < 4; tm++) {
#pragma unroll
    for (int tn = 0; tn < 4; tn++) {
#pragma unroll
      for (int r = 0; r < 4; r++) {
        int row = m0 + wm * 64 + tm * 16 + quad * 4 + r;
        int gcol = n0 + wn * 64 + tn * 16 + l16;
        float v = acc[tm][tn][r];
        if (isQ) v = v * SCALE + bias[gcol];
        outp[(size_t)row * DIMD + gcol] = f2bf(v);
      }
    }
  }
}

// ---------------------------------------------------------------------------
// attn: O = sigmoid(Q K^T) V  via operand-swap (no P LDS round-trip):
//   S^T = mfma32_bf16(A=K, B=Q)  -> lane holds (i=l16, j=quad*4+r)
//   sigmoid+pkrtz in-register    -> exactly the B-frag of mfma_16x16x16_f16
//   O^T += mfma16_f16(A=V^T, B=P) -> lane holds (d=quad*4+r, i=l16): float4 out
// BM=128 (4 waves x 2 i-subtiles), j-tile 64. grid (16, 32).
// ---------------------------------------------------------------------------
__global__ __launch_bounds__(256) void attn(const unsigned short* __restrict__ qb,
                                            const unsigned short* __restrict__ kb,
                                            const unsigned short* __restrict__ xtf,
                                            float* __restrict__ out) {
  __shared__ __align__(16) unsigned short Kls[64][72];
  __shared__ __align__(16) unsigned short Vtls[64][72];
  const int it = blockIdx.x, bh = blockIdx.y;
  const int b = bh >> 3, h = bh & 7;
  const int i0 = it * 128;
  const int tid = threadIdx.x;
  const int wave = tid >> 6, lane = tid & 63;
  const int quad = lane >> 4, l16 = lane & 15;

  // Q B-fragments (n=i=l16, k=d=quad*8+...), two i-subtiles per wave
  bf16x8 qfrag[2][2];
  int irow[2];
#pragma unroll
  for (int s_ = 0; s_ < 2; s_++) {
    irow[s_] = i0 + (wave * 2 + s_) * 16 + l16;
    const unsigned short* qp =
        qb + ((size_t)b * NN + irow[s_]) * DIMD + h * DKK + quad * 8;
    qfrag[s_][0] = *(const bf16x8*)qp;
    qfrag[s_][1] = *(const bf16x8*)(qp + 32);
  }

  f32x4 o[2][4];
#pragma unroll
  for (int s_ = 0; s_ < 2; s_++)
#pragma unroll
    for (int td = 0; td < 4; td++) o[s_][td] = (f32x4){0.f, 0.f, 0.f, 0.f};

  const unsigned short* kbase = kb + (size_t)b * NN * DIMD + h * DKK;
  const unsigned short* vbase = xtf + ((size_t)b * DIMD + h * DKK) * NN;

  for (int j0 = 0; j0 < NN; j0 += 64) {
    __syncthreads();
#pragma unroll
    for (int r = 0; r < 2; r++) {
      int idx = tid + r * 256;
      int row = idx >> 3, c = idx & 7;
      *(uint4*)&Kls[row][c * 8] =
          *(const uint4*)(kbase + (size_t)(j0 + row) * DIMD + c * 8);
      *(uint4*)&Vtls[row][c * 8] =
          *(const uint4*)(vbase + (size_t)row * NN + j0 + c * 8);
    }
    __syncthreads();

    // S^T + sigmoid -> P fragments (registers only)
    f16x4 pfrag[2][4];
#pragma unroll
    for (int t = 0; t < 4; t++) {
      bf16x8 kf0 = *(const bf16x8*)&Kls[t * 16 + l16][quad * 8];
      bf16x8 kf1 = *(const bf16x8*)&Kls[t * 16 + l16][quad * 8 + 32];
#pragma unroll
      for (int s_ = 0; s_ < 2; s_++) {
        f32x4 sv = (f32x4){0.f, 0.f, 0.f, 0.f};
        sv = __builtin_amdgcn_mfma_f32_16x16x32_bf16(kf0, qfrag[s_][0], sv, 0, 0, 0);
        sv = __builtin_amdgcn_mfma_f32_16x16x32_bf16(kf1, qfrag[s_][1], sv, 0, 0, 0);
        fp16v2 lo = __builtin_amdgcn_cvt_pkrtz(sigmoidf(sv[0]), sigmoidf(sv[1]));
        fp16v2 hi = __builtin_amdgcn_cvt_pkrtz(sigmoidf(sv[2]), sigmoidf(sv[3]));
        fp16v4 p;
        p.x = lo.x; p.y = lo.y; p.z = hi.x; p.w = hi.y;
        pfrag[s_][t] = __builtin_bit_cast(f16x4, p);
      }
    }

    // O^T += V^T P : A-frag = V^T[d=td*16+l16][j=t*16+quad*4+0..3]
#pragma unroll
    for (int td = 0; td < 4; td++) {
#pragma unroll
      for (int t = 0; t < 4; t++) {
        f16x4 vf = *(const f16x4*)&Vtls[td * 16 + l16][t * 16 + quad * 4];
        o[0][td] = __builtin_amdgcn_mfma_f32_16x16x16f16(vf, pfrag[0][t], o[0][td], 0, 0, 0);
        o[1][td] = __builtin_amdgcn_mfma_f32_16x16x16f16(vf, pfrag[1][t], o[1][td], 0, 0, 0);
      }
    }
  }

  // epilogue: lane holds O^T[d=quad*4+r][i=l16] -> float4 along d
#pragma unroll
  for (int s_ = 0; s_ < 2; s_++) {
#pragma unroll
    for (int td = 0; td < 4; td++) {
      float* op = out + ((size_t)b * NN + irow[s_]) * DIMD + h * DKK + td * 16 + quad * 4;
      *(f32x4*)op = o[s_][td];
    }
  }
}

// ---------------------------------------------------------------------------
extern "C" void kernel_launch(void* const* d_in, const int* in_sizes, int n_in,
                              void* d_out, int out_size, void* d_ws, size_t ws_size,
                              hipStream_t stream) {
  const float* x = (const float*)d_in[0];
  const float* Wq = (const float*)d_in[1];
  const float* Wk = (const float*)d_in[2];
  const float* bias = (const float*)d_in[3]; // [1,8,1,64] flat = 512
  float* out = (float*)d_out;

  unsigned short* ws = (unsigned short*)d_ws;
  unsigned short* xb = ws;                         // 4,194,304
  unsigned short* xtf = xb + (size_t)MTOT * DIMD;  // 4,194,304 (f16 bits)
  unsigned short* wtq = xtf + (size_t)MTOT * DIMD; // 262,144
  unsigned short* wtk = wtq + (size_t)DIMD * DIMD; // 262,144
  unsigned short* qb = wtk + (size_t)DIMD * DIMD;  // 4,194,304
  unsigned short* kb = qb + (size_t)MTOT * DIMD;   // 4,194,304

  prep_x<<<dim3(32, 8, 4), 256, 0, stream>>>(x, xb, xtf);
  prep_w<<<dim3(8, 8, 2), 256, 0, stream>>>(Wq, Wk, wtq, wtk);
  qk_gemm<<<dim3(64, 8), 256, 0, stream>>>(xb, wtq, wtk, bias, qb, kb);
  attn<<<dim3(16, 32), 256, 0, stream>>>(qb, kb, xtf, out);
}

// Round 4
// 174.760 us; speedup vs baseline: 1.0571x; 1.0309x over previous
//
#include <hip/hip_runtime.h>
#include <hip/hip_bf16.h>
#include <stdint.h>

// Problem constants
#define BB 4
#define NN 2048
#define DIMD 512
#define HH 8
#define DKK 64
#define MTOT (BB * NN)          // 8192
constexpr float SCALE = 0.125f; // DK^-0.5

typedef __attribute__((ext_vector_type(4))) float f32x4;
typedef __attribute__((ext_vector_type(8))) short bf16x8;   // 8 bf16 (4 VGPRs)
typedef __attribute__((ext_vector_type(4))) _Float16 f16x4; // 4 f16 (2 VGPRs)
typedef __attribute__((ext_vector_type(2))) __fp16 fp16v2;  // cvt_pkrtz result type
typedef __attribute__((ext_vector_type(4))) __fp16 fp16v4;

union pack8 { unsigned short s[8]; uint4 v; };

__device__ __forceinline__ unsigned short f2bf(float f) {
  union { float f; uint32_t u; } v; v.f = f;
  uint32_t u = v.u;
  return (unsigned short)((u + 0x7FFFu + ((u >> 16) & 1u)) >> 16); // RNE
}

__device__ __forceinline__ unsigned short f2h(float f) {
  union { _Float16 h; unsigned short u; } c; c.h = (_Float16)f;
  return c.u;
}

__device__ __forceinline__ float sigmoidf(float x) {
  return __builtin_amdgcn_rcpf(1.0f + __expf(-x));
}

// ---------------------------------------------------------------------------
// prep_x: x fp32 [B][N][DIM] -> xb bf16 [B*N][DIM] (GEMM A)
//                           and xtf f16  [B][DIM][N] (V^T for PV f16 MFMA)
// grid: (32 n-tiles, 8 d-tiles, 4 batch), 256 threads. All global stores uint4.
// ---------------------------------------------------------------------------
__global__ __launch_bounds__(256) void prep_x(const float* __restrict__ x,
                                              unsigned short* __restrict__ xb,
                                              unsigned short* __restrict__ xtf) {
  __shared__ __align__(16) unsigned short T[64][72]; // [d][n]
  const int b = blockIdx.z, nt = blockIdx.x, dt = blockIdx.y;
  const int tid = threadIdx.x;
  const int n0 = nt * 64, d0 = dt * 64;
  const float* src = x + ((size_t)b * NN + n0) * DIMD + d0;
#pragma unroll
  for (int r = 0; r < 2; r++) {
    int idx = tid + r * 256;          // 0..511
    int nl = idx >> 3, c = idx & 7;   // row 0..63, 8-elem chunk 0..7
    const float* sp = src + (size_t)nl * DIMD + c * 8;
    pack8 pb;
#pragma unroll
    for (int k = 0; k < 8; k++) {
      float f = sp[k];
      pb.s[k] = f2bf(f);
      T[c * 8 + k][nl] = f2h(f);
    }
    *(uint4*)(xb + ((size_t)b * NN + n0 + nl) * DIMD + d0 + c * 8) = pb.v;
  }
  __syncthreads();
  unsigned short* dst = xtf + ((size_t)b * DIMD + d0) * NN + n0;
#pragma unroll
  for (int r = 0; r < 2; r++) {
    int idx = tid + r * 256;
    int dl = idx >> 3, c = idx & 7;
    uint4 v = *(const uint4*)&T[dl][c * 8];
    *(uint4*)(dst + (size_t)dl * NN + c * 8) = v;
  }
}

// ---------------------------------------------------------------------------
// prep_w: W fp32 [K=512][N=512] -> Wt bf16 [N][K]; grid.z selects Wq/Wk
// ---------------------------------------------------------------------------
__global__ __launch_bounds__(256) void prep_w(const float* __restrict__ wq,
                                              const float* __restrict__ wk,
                                              unsigned short* __restrict__ wtq,
                                              unsigned short* __restrict__ wtk) {
  __shared__ __align__(16) unsigned short T[64][72]; // [n][k]
  const float* w = blockIdx.z ? wk : wq;
  unsigned short* wt = blockIdx.z ? wtk : wtq;
  const int kt = blockIdx.x, nt = blockIdx.y;
  const int tid = threadIdx.x;
  const int k0 = kt * 64, n0 = nt * 64;
#pragma unroll
  for (int r = 0; r < 16; r++) {
    int idx = tid + r * 256;
    int kl = idx >> 6, nl = idx & 63;
    T[nl][kl] = f2bf(w[(size_t)(k0 + kl) * DIMD + n0 + nl]);
  }
  __syncthreads();
#pragma unroll
  for (int r = 0; r < 2; r++) {
    int idx = tid + r * 256;
    int nl = idx >> 3, c = idx & 7;
    uint4 v = *(const uint4*)&T[nl][c * 8];
    *(uint4*)(wt + (size_t)(n0 + nl) * DIMD + k0 + c * 8) = v;
  }
}

// ---------------------------------------------------------------------------
// qk_gemm: 128x128 tile, 4 waves in 2x2, each wave 64x64 (4x4 16x16 accs).
//   grid (64 m-blocks, 8 n-blocks): nb 0..3 -> Q (scale+bias), 4..7 -> K.
// ---------------------------------------------------------------------------
__global__ __launch_bounds__(256) void qk_gemm(const unsigned short* __restrict__ xb,
                                               const unsigned short* __restrict__ wtq,
                                               const unsigned short* __restrict__ wtk,
                                               const float* __restrict__ bias,
                                               unsigned short* __restrict__ qout,
                                               unsigned short* __restrict__ kout) {
  __shared__ __align__(16) unsigned short Als[128][72];
  __shared__ __align__(16) unsigned short Bls[128][72];
  const int mb = blockIdx.x, nb = blockIdx.y;
  const bool isQ = (nb < 4);
  const unsigned short* wt = isQ ? wtq : wtk;
  unsigned short* outp = isQ ? qout : kout;
  const int n0 = (nb & 3) * 128, m0 = mb * 128;
  const int tid = threadIdx.x;
  const int wave = tid >> 6, lane = tid & 63;
  const int quad = lane >> 4, l16 = lane & 15;
  const int wm = wave >> 1, wn = wave & 1;

  f32x4 acc[4][4];
#pragma unroll
  for (int a = 0; a < 4; a++)
#pragma unroll
    for (int c = 0; c < 4; c++) acc[a][c] = (f32x4){0.f, 0.f, 0.f, 0.f};

  for (int k0 = 0; k0 < DIMD; k0 += 64) {
    __syncthreads();
#pragma unroll
    for (int r = 0; r < 4; r++) {
      int idx = tid + r * 256;          // 0..1023
      int row = idx >> 3, c = idx & 7;  // 128 rows x 8 16B-chunks
      *(uint4*)&Als[row][c * 8] =
          *(const uint4*)(xb + (size_t)(m0 + row) * DIMD + k0 + c * 8);
      *(uint4*)&Bls[row][c * 8] =
          *(const uint4*)(wt + (size_t)(n0 + row) * DIMD + k0 + c * 8);
    }
    __syncthreads();
#pragma unroll
    for (int ks = 0; ks < 2; ks++) {
      bf16x8 af[4], bfr[4];
#pragma unroll
      for (int t = 0; t < 4; t++) {
        af[t] = *(const bf16x8*)&Als[wm * 64 + t * 16 + l16][quad * 8 + ks * 32];
        bfr[t] = *(const bf16x8*)&Bls[wn * 64 + t * 16 + l16][quad * 8 + ks * 32];
      }
#pragma unroll
      for (int tm = 0; tm < 4; tm++)
#pragma unroll
        for (int tn = 0; tn < 4; tn++)
          acc[tm][tn] =
              __builtin_amdgcn_mfma_f32_16x16x32_bf16(af[tm], bfr[tn], acc[tm][tn], 0, 0, 0);
    }
  }
  // epilogue: C layout col=l16, row=quad*4+r
#pragma unroll
  for (int tm = 0; tm < 4; tm++) {
#pragma unroll
    for (int tn = 0; tn < 4; tn++) {
#pragma unroll
      for (int r = 0; r < 4; r++) {
        int row = m0 + wm * 64 + tm * 16 + quad * 4 + r;
        int gcol = n0 + wn * 64 + tn * 16 + l16;
        float v = acc[tm][tn][r];
        if (isQ) v = v * SCALE + bias[gcol];
        outp[(size_t)row * DIMD + gcol] = f2bf(v);
      }
    }
  }
}

// ---------------------------------------------------------------------------
// attn: O = sigmoid(Q K^T) V  via operand-swap (register P, no LDS round-trip)
//   BM=64 (4 waves x 1 i-subtile), j-tile 128, grid (32, 32) -> 4 blocks/CU.
//   S^T = mfma32_bf16(A=K, B=Q); sigmoid+pkrtz in-register -> B-frag of
//   mfma_16x16x16f16; O^T += mfma16_f16(A=V^T, B=P); float4 epilogue.
// ---------------------------------------------------------------------------
__global__ __launch_bounds__(256) void attn(const unsigned short* __restrict__ qb,
                                            const unsigned short* __restrict__ kb,
                                            const unsigned short* __restrict__ xtf,
                                            float* __restrict__ out) {
  __shared__ __align__(16) unsigned short Kls[128][72];   // [j][dk]
  __shared__ __align__(16) unsigned short Vtls[64][136];  // [d][j]
  const int it = blockIdx.x, bh = blockIdx.y;
  const int b = bh >> 3, h = bh & 7;
  const int i0 = it * 64;
  const int tid = threadIdx.x;
  const int wave = tid >> 6, lane = tid & 63;
  const int quad = lane >> 4, l16 = lane & 15;

  // Q B-fragment (n=i=l16, k=d=quad*8+...)
  const int irow = i0 + wave * 16 + l16;
  bf16x8 qfrag0, qfrag1;
  {
    const unsigned short* qp = qb + ((size_t)b * NN + irow) * DIMD + h * DKK + quad * 8;
    qfrag0 = *(const bf16x8*)qp;
    qfrag1 = *(const bf16x8*)(qp + 32);
  }

  f32x4 o[4];
#pragma unroll
  for (int td = 0; td < 4; td++) o[td] = (f32x4){0.f, 0.f, 0.f, 0.f};

  const unsigned short* kbase = kb + (size_t)b * NN * DIMD + h * DKK;
  const unsigned short* vbase = xtf + ((size_t)b * DIMD + h * DKK) * NN;

  for (int j0 = 0; j0 < NN; j0 += 128) {
    __syncthreads();
#pragma unroll
    for (int r = 0; r < 4; r++) {
      int idx = tid + r * 256;              // 0..1023
      int row = idx >> 3, c = idx & 7;      // K: 128 rows x 8 chunks
      *(uint4*)&Kls[row][c * 8] =
          *(const uint4*)(kbase + (size_t)(j0 + row) * DIMD + c * 8);
      int rowd = idx >> 4, cv = idx & 15;   // Vt: 64 rows x 16 chunks
      *(uint4*)&Vtls[rowd][cv * 8] =
          *(const uint4*)(vbase + (size_t)rowd * NN + j0 + cv * 8);
    }
    __syncthreads();

#pragma unroll
    for (int t = 0; t < 8; t++) {
      // S^T tile: lane holds (i=l16, j=t*16+quad*4+r)
      bf16x8 kf0 = *(const bf16x8*)&Kls[t * 16 + l16][quad * 8];
      bf16x8 kf1 = *(const bf16x8*)&Kls[t * 16 + l16][quad * 8 + 32];
      f32x4 sv = (f32x4){0.f, 0.f, 0.f, 0.f};
      sv = __builtin_amdgcn_mfma_f32_16x16x32_bf16(kf0, qfrag0, sv, 0, 0, 0);
      sv = __builtin_amdgcn_mfma_f32_16x16x32_bf16(kf1, qfrag1, sv, 0, 0, 0);
      fp16v2 lo = __builtin_amdgcn_cvt_pkrtz(sigmoidf(sv[0]), sigmoidf(sv[1]));
      fp16v2 hi = __builtin_amdgcn_cvt_pkrtz(sigmoidf(sv[2]), sigmoidf(sv[3]));
      fp16v4 p;
      p.x = lo.x; p.y = lo.y; p.z = hi.x; p.w = hi.y;
      f16x4 pfrag = __builtin_bit_cast(f16x4, p);
      // O^T += V^T P
#pragma unroll
      for (int td = 0; td < 4; td++) {
        f16x4 vf = *(const f16x4*)&Vtls[td * 16 + l16][t * 16 + quad * 4];
        o[td] = __builtin_amdgcn_mfma_f32_16x16x16f16(vf, pfrag, o[td], 0, 0, 0);
      }
    }
  }

  // epilogue: lane holds O^T[d=quad*4+r][i=l16] -> float4 along d
#pragma unroll
  for (int td = 0; td < 4; td++) {
    float* op = out + ((size_t)b * NN + irow) * DIMD + h * DKK + td * 16 + quad * 4;
    *(f32x4*)op = o[td];
  }
}

// ---------------------------------------------------------------------------
extern "C" void kernel_launch(void* const* d_in, const int* in_sizes, int n_in,
                              void* d_out, int out_size, void* d_ws, size_t ws_size,
                              hipStream_t stream) {
  const float* x = (const float*)d_in[0];
  const float* Wq = (const float*)d_in[1];
  const float* Wk = (const float*)d_in[2];
  const float* bias = (const float*)d_in[3]; // [1,8,1,64] flat = 512
  float* out = (float*)d_out;

  unsigned short* ws = (unsigned short*)d_ws;
  unsigned short* xb = ws;                         // 4,194,304
  unsigned short* xtf = xb + (size_t)MTOT * DIMD;  // 4,194,304 (f16 bits)
  unsigned short* wtq = xtf + (size_t)MTOT * DIMD; // 262,144
  unsigned short* wtk = wtq + (size_t)DIMD * DIMD; // 262,144
  unsigned short* qb = wtk + (size_t)DIMD * DIMD;  // 4,194,304
  unsigned short* kb = qb + (size_t)MTOT * DIMD;   // 4,194,304

  prep_x<<<dim3(32, 8, 4), 256, 0, stream>>>(x, xb, xtf);
  prep_w<<<dim3(8, 8, 2), 256, 0, stream>>>(Wq, Wk, wtq, wtk);
  qk_gemm<<<dim3(64, 8), 256, 0, stream>>>(xb, wtq, wtk, bias, qb, kb);
  attn<<<dim3(32, 32), 256, 0, stream>>>(qb, kb, xtf, out);
}

// Round 5
// 159.539 us; speedup vs baseline: 1.1580x; 1.0954x over previous
//
#include <hip/hip_runtime.h>
#include <hip/hip_bf16.h>
#include <stdint.h>

// Problem constants
#define BB 4
#define NN 2048
#define DIMD 512
#define HH 8
#define DKK 64
#define MTOT (BB * NN)          // 8192
constexpr float SCALE = 0.125f; // DK^-0.5

typedef __attribute__((ext_vector_type(4))) float f32x4;
typedef __attribute__((ext_vector_type(2))) float f32x2;
typedef __attribute__((ext_vector_type(8))) short bf16x8;   // 8 bf16 (4 VGPRs)
typedef __attribute__((ext_vector_type(4))) _Float16 f16x4; // 4 f16 (2 VGPRs)
typedef __attribute__((ext_vector_type(2))) __fp16 fp16v2;  // cvt_pkrtz result
typedef __attribute__((ext_vector_type(4))) __fp16 fp16v4;
typedef __attribute__((ext_vector_type(2))) unsigned int u32x2;

union pack8 { unsigned short s[8]; uint4 v; };
union fragu { u32x2 h[2]; bf16x8 v; };

__device__ __forceinline__ unsigned short f2bf(float f) {
  union { float f; uint32_t u; } v; v.f = f;
  uint32_t u = v.u;
  return (unsigned short)((u + 0x7FFFu + ((u >> 16) & 1u)) >> 16); // RNE
}

__device__ __forceinline__ unsigned short f2h(float f) {
  union { _Float16 h; unsigned short u; } c; c.h = (_Float16)f;
  return c.u;
}

// LDS helpers for stride-68 (8B-aligned) rows: explicit b64 ops, no b128
__device__ __forceinline__ bf16x8 ld_frag(const unsigned short* p) {
  fragu f;
  f.h[0] = *(const u32x2*)p;
  f.h[1] = *(const u32x2*)(p + 4);
  return f.v;
}
__device__ __forceinline__ void st8(unsigned short* p, uint4 v) {
  *(u32x2*)p = (u32x2){v.x, v.y};
  *(u32x2*)(p + 4) = (u32x2){v.z, v.w};
}

// sigmoid(x) via e=exp(-|x|) (1 transcendental) + deg-3 minimax poly for
// 1/(1+e)-0.5 on e in (0,1], then sign fold. Max err ~2e-3.
__device__ __forceinline__ f16x4 sig_pack(f32x4 sv) {
  float e0 = __expf(-__builtin_fabsf(sv[0]));
  float e1 = __expf(-__builtin_fabsf(sv[1]));
  float e2 = __expf(-__builtin_fabsf(sv[2]));
  float e3 = __expf(-__builtin_fabsf(sv[3]));
  const f32x2 c3 = {-0.22184f, -0.22184f};
  const f32x2 c2 = {0.66550f, 0.66550f};
  const f32x2 c1 = {-0.94280f, -0.94280f};
  const f32x2 c0 = {0.49826f, 0.49826f};
  f32x2 eA = {e0, e1}, eB = {e2, e3};
  f32x2 pA = __builtin_elementwise_fma(
      __builtin_elementwise_fma(__builtin_elementwise_fma(c3, eA, c2), eA, c1),
      eA, c0);
  f32x2 pB = __builtin_elementwise_fma(
      __builtin_elementwise_fma(__builtin_elementwise_fma(c3, eB, c2), eB, c1),
      eB, c0);
  float r0 = __builtin_copysignf(pA.x, sv[0]) + 0.5f;
  float r1 = __builtin_copysignf(pA.y, sv[1]) + 0.5f;
  float r2 = __builtin_copysignf(pB.x, sv[2]) + 0.5f;
  float r3 = __builtin_copysignf(pB.y, sv[3]) + 0.5f;
  fp16v2 lo = __builtin_amdgcn_cvt_pkrtz(r0, r1);
  fp16v2 hi = __builtin_amdgcn_cvt_pkrtz(r2, r3);
  fp16v4 p;
  p.x = lo.x; p.y = lo.y; p.z = hi.x; p.w = hi.y;
  return __builtin_bit_cast(f16x4, p);
}

// ---------------------------------------------------------------------------
// prep_x: x fp32 [B][N][DIM] -> xb bf16 [B*N][DIM] and xtf f16 [B][DIM][N]
// ---------------------------------------------------------------------------
__global__ __launch_bounds__(256) void prep_x(const float* __restrict__ x,
                                              unsigned short* __restrict__ xb,
                                              unsigned short* __restrict__ xtf) {
  __shared__ __align__(16) unsigned short T[64][72]; // [d][n]
  const int b = blockIdx.z, nt = blockIdx.x, dt = blockIdx.y;
  const int tid = threadIdx.x;
  const int n0 = nt * 64, d0 = dt * 64;
  const float* src = x + ((size_t)b * NN + n0) * DIMD + d0;
#pragma unroll
  for (int r = 0; r < 2; r++) {
    int idx = tid + r * 256;
    int nl = idx >> 3, c = idx & 7;
    const float* sp = src + (size_t)nl * DIMD + c * 8;
    pack8 pb;
#pragma unroll
    for (int k = 0; k < 8; k++) {
      float f = sp[k];
      pb.s[k] = f2bf(f);
      T[c * 8 + k][nl] = f2h(f);
    }
    *(uint4*)(xb + ((size_t)b * NN + n0 + nl) * DIMD + d0 + c * 8) = pb.v;
  }
  __syncthreads();
  unsigned short* dst = xtf + ((size_t)b * DIMD + d0) * NN + n0;
#pragma unroll
  for (int r = 0; r < 2; r++) {
    int idx = tid + r * 256;
    int dl = idx >> 3, c = idx & 7;
    uint4 v = *(const uint4*)&T[dl][c * 8];
    *(uint4*)(dst + (size_t)dl * NN + c * 8) = v;
  }
}

// ---------------------------------------------------------------------------
// prep_w: W fp32 [K=512][N=512] -> Wt bf16 [N][K]; grid.z selects Wq/Wk
// ---------------------------------------------------------------------------
__global__ __launch_bounds__(256) void prep_w(const float* __restrict__ wq,
                                              const float* __restrict__ wk,
                                              unsigned short* __restrict__ wtq,
                                              unsigned short* __restrict__ wtk) {
  __shared__ __align__(16) unsigned short T[64][72];
  const float* w = blockIdx.z ? wk : wq;
  unsigned short* wt = blockIdx.z ? wtk : wtq;
  const int kt = blockIdx.x, nt = blockIdx.y;
  const int tid = threadIdx.x;
  const int k0 = kt * 64, n0 = nt * 64;
#pragma unroll
  for (int r = 0; r < 16; r++) {
    int idx = tid + r * 256;
    int kl = idx >> 6, nl = idx & 63;
    T[nl][kl] = f2bf(w[(size_t)(k0 + kl) * DIMD + n0 + nl]);
  }
  __syncthreads();
#pragma unroll
  for (int r = 0; r < 2; r++) {
    int idx = tid + r * 256;
    int nl = idx >> 3, c = idx & 7;
    uint4 v = *(const uint4*)&T[nl][c * 8];
    *(uint4*)(wt + (size_t)(n0 + nl) * DIMD + k0 + c * 8) = v;
  }
}

// ---------------------------------------------------------------------------
// qk_gemm: 128x128 tile, 4 waves 2x2, LDS stride 68 (b64, conflict-free)
// ---------------------------------------------------------------------------
__global__ __launch_bounds__(256) void qk_gemm(const unsigned short* __restrict__ xb,
                                               const unsigned short* __restrict__ wtq,
                                               const unsigned short* __restrict__ wtk,
                                               const float* __restrict__ bias,
                                               unsigned short* __restrict__ qout,
                                               unsigned short* __restrict__ kout) {
  __shared__ __align__(16) unsigned short Als[128][68];
  __shared__ __align__(16) unsigned short Bls[128][68];
  const int mb = blockIdx.x, nb = blockIdx.y;
  const bool isQ = (nb < 4);
  const unsigned short* wt = isQ ? wtq : wtk;
  unsigned short* outp = isQ ? qout : kout;
  const int n0 = (nb & 3) * 128, m0 = mb * 128;
  const int tid = threadIdx.x;
  const int wave = tid >> 6, lane = tid & 63;
  const int quad = lane >> 4, l16 = lane & 15;
  const int wm = wave >> 1, wn = wave & 1;

  f32x4 acc[4][4];
#pragma unroll
  for (int a = 0; a < 4; a++)
#pragma unroll
    for (int c = 0; c < 4; c++) acc[a][c] = (f32x4){0.f, 0.f, 0.f, 0.f};

  for (int k0 = 0; k0 < DIMD; k0 += 64) {
    __syncthreads();
#pragma unroll
    for (int r = 0; r < 4; r++) {
      int idx = tid + r * 256;
      int row = idx >> 3, c = idx & 7;
      st8(&Als[row][c * 8], *(const uint4*)(xb + (size_t)(m0 + row) * DIMD + k0 + c * 8));
      st8(&Bls[row][c * 8], *(const uint4*)(wt + (size_t)(n0 + row) * DIMD + k0 + c * 8));
    }
    __syncthreads();
#pragma unroll
    for (int ks = 0; ks < 2; ks++) {
      bf16x8 af[4], bfr[4];
#pragma unroll
      for (int t = 0; t < 4; t++) {
        af[t] = ld_frag(&Als[wm * 64 + t * 16 + l16][quad * 8 + ks * 32]);
        bfr[t] = ld_frag(&Bls[wn * 64 + t * 16 + l16][quad * 8 + ks * 32]);
      }
#pragma unroll
      for (int tm = 0; tm < 4; tm++)
#pragma unroll
        for (int tn = 0; tn < 4; tn++)
          acc[tm][tn] =
              __builtin_amdgcn_mfma_f32_16x16x32_bf16(af[tm], bfr[tn], acc[tm][tn], 0, 0, 0);
    }
  }
#pragma unroll
  for (int tm = 0; tm < 4; tm++) {
#pragma unroll
    for (int tn = 0; tn < 4; tn++) {
#pragma unroll
      for (int r = 0; r < 4; r++) {
        int row = m0 + wm * 64 + tm * 16 + quad * 4 + r;
        int gcol = n0 + wn * 64 + tn * 16 + l16;
        float v = acc[tm][tn][r];
        if (isQ) v = v * SCALE + bias[gcol];
        outp[(size_t)row * DIMD + gcol] = f2bf(v);
      }
    }
  }
}

// ---------------------------------------------------------------------------
// attn: O = sigmoid(Q K^T) V, register-P operand-swap.
//   512 threads = 8 waves = 2 j-groups x 4 waves. BM=128 (wave: 2 i-subtiles
//   of 16), group g covers j in [g*1024, g*1024+1024) in 16 tiles of 64.
//   Partial O^T combined through LDS at the end. grid (16, 32).
//   LDS rows stride 68 shorts (b64 conflict-free).
// ---------------------------------------------------------------------------
__global__ __launch_bounds__(512, 4) void attn(const unsigned short* __restrict__ qb,
                                               const unsigned short* __restrict__ kb,
                                               const unsigned short* __restrict__ xtf,
                                               float* __restrict__ out) {
  __shared__ __align__(16) char smem[34816];
  unsigned short* Kbase = (unsigned short*)smem;   // [2][64][68]
  unsigned short* Vbase = Kbase + 2 * 64 * 68;     // [2][64][68]
  float* Obuf = (float*)smem;                      // [128][68] (reused after loop)

  const int it = blockIdx.x, bh = blockIdx.y;
  const int b = bh >> 3, h = bh & 7;
  const int i0 = it * 128;
  const int tid = threadIdx.x;
  const int lane = tid & 63;
  const int grp = tid >> 8;          // j-group 0/1
  const int wv = (tid >> 6) & 3;     // wave within group
  const int gtid = tid & 255;
  const int quad = lane >> 4, l16 = lane & 15;

  // Q B-fragments for 2 i-subtiles
  bf16x8 qf[2][2];
  int irow[2];
#pragma unroll
  for (int s_ = 0; s_ < 2; s_++) {
    irow[s_] = i0 + wv * 32 + s_ * 16 + l16;
    const unsigned short* qp = qb + ((size_t)b * NN + irow[s_]) * DIMD + h * DKK + quad * 8;
    qf[s_][0] = *(const bf16x8*)qp;
    qf[s_][1] = *(const bf16x8*)(qp + 32);
  }

  f32x4 o[2][4];
#pragma unroll
  for (int s_ = 0; s_ < 2; s_++)
#pragma unroll
    for (int td = 0; td < 4; td++) o[s_][td] = (f32x4){0.f, 0.f, 0.f, 0.f};

  const unsigned short* kbase = kb + (size_t)b * NN * DIMD + h * DKK;
  const unsigned short* vbase = xtf + ((size_t)b * DIMD + h * DKK) * NN;
  unsigned short* Kg = Kbase + grp * (64 * 68);
  unsigned short* Vg = Vbase + grp * (64 * 68);
  const int jbase = grp * 1024;

  for (int itr = 0; itr < 16; itr++) {
    const int j0 = jbase + itr * 64;
    __syncthreads();
#pragma unroll
    for (int r = 0; r < 2; r++) {
      int idx = gtid + r * 256;         // 0..511
      int row = idx >> 3, c = idx & 7;  // 64 rows x 8 chunks
      st8(&Kg[row * 68 + c * 8], *(const uint4*)(kbase + (size_t)(j0 + row) * DIMD + c * 8));
      st8(&Vg[row * 68 + c * 8], *(const uint4*)(vbase + (size_t)row * NN + j0 + c * 8));
    }
    __syncthreads();

#pragma unroll
    for (int t = 0; t < 4; t++) {
      bf16x8 kf0 = ld_frag(&Kg[(t * 16 + l16) * 68 + quad * 8]);
      bf16x8 kf1 = ld_frag(&Kg[(t * 16 + l16) * 68 + quad * 8 + 32]);
      f16x4 pf[2];
#pragma unroll
      for (int s_ = 0; s_ < 2; s_++) {
        f32x4 sv = (f32x4){0.f, 0.f, 0.f, 0.f};
        sv = __builtin_amdgcn_mfma_f32_16x16x32_bf16(kf0, qf[s_][0], sv, 0, 0, 0);
        sv = __builtin_amdgcn_mfma_f32_16x16x32_bf16(kf1, qf[s_][1], sv, 0, 0, 0);
        pf[s_] = sig_pack(sv);
      }
#pragma unroll
      for (int td = 0; td < 4; td++) {
        f16x4 vf = __builtin_bit_cast(
            f16x4, *(const u32x2*)&Vg[(td * 16 + l16) * 68 + t * 16 + quad * 4]);
        o[0][td] = __builtin_amdgcn_mfma_f32_16x16x16f16(vf, pf[0], o[0][td], 0, 0, 0);
        o[1][td] = __builtin_amdgcn_mfma_f32_16x16x16f16(vf, pf[1], o[1][td], 0, 0, 0);
      }
    }
  }

  // combine the two j-groups' partial O^T through LDS; group 0 stores.
  __syncthreads();
  if (grp == 1) {
#pragma unroll
    for (int s_ = 0; s_ < 2; s_++)
#pragma unroll
      for (int td = 0; td < 4; td++)
        *(f32x4*)&Obuf[(wv * 32 + s_ * 16 + l16) * 68 + td * 16 + quad * 4] = o[s_][td];
  }
  __syncthreads();
  if (grp == 0) {
#pragma unroll
    for (int s_ = 0; s_ < 2; s_++) {
#pragma unroll
      for (int td = 0; td < 4; td++) {
        o[s_][td] += *(const f32x4*)&Obuf[(wv * 32 + s_ * 16 + l16) * 68 + td * 16 + quad * 4];
        float* op = out + ((size_t)b * NN + irow[s_]) * DIMD + h * DKK + td * 16 + quad * 4;
        *(f32x4*)op = o[s_][td];
      }
    }
  }
}

// ---------------------------------------------------------------------------
extern "C" void kernel_launch(void* const* d_in, const int* in_sizes, int n_in,
                              void* d_out, int out_size, void* d_ws, size_t ws_size,
                              hipStream_t stream) {
  const float* x = (const float*)d_in[0];
  const float* Wq = (const float*)d_in[1];
  const float* Wk = (const float*)d_in[2];
  const float* bias = (const float*)d_in[3]; // [1,8,1,64] flat = 512
  float* out = (float*)d_out;

  unsigned short* ws = (unsigned short*)d_ws;
  unsigned short* xb = ws;                         // 4,194,304
  unsigned short* xtf = xb + (size_t)MTOT * DIMD;  // 4,194,304 (f16 bits)
  unsigned short* wtq = xtf + (size_t)MTOT * DIMD; // 262,144
  unsigned short* wtk = wtq + (size_t)DIMD * DIMD; // 262,144
  unsigned short* qb = wtk + (size_t)DIMD * DIMD;  // 4,194,304
  unsigned short* kb = qb + (size_t)MTOT * DIMD;   // 4,194,304

  prep_x<<<dim3(32, 8, 4), 256, 0, stream>>>(x, xb, xtf);
  prep_w<<<dim3(8, 8, 2), 256, 0, stream>>>(Wq, Wk, wtq, wtk);
  qk_gemm<<<dim3(64, 8), 256, 0, stream>>>(xb, wtq, wtk, bias, qb, kb);
  attn<<<dim3(16, 32), 512, 0, stream>>>(qb, kb, xtf, out);
}